// Round 5
// baseline (289.648 us; speedup 1.0000x reference)
//
#include <hip/hip_runtime.h>
#include <math.h>

// Problem constants (match reference)
constexpr int NB   = 8;            // batch
constexpr int ND   = 8;            // embedding dim
constexpr int NH   = 512;
constexpr int NW   = 1024;
constexpr int NP   = NH * NW;      // pixels per image = 524288
constexpr int NG   = NP / 4;       // float4 groups per image = 131072
constexpr int NK   = 5;            // instance labels 1..NK
constexpr int NVAL = NK * ND + NK; // 45 reduced values in pass 1

constexpr float DELTA_V     = 0.5f;
constexpr float TWO_DELTA_D = 6.0f;   // 2 * DELTA_D
constexpr float GAMMA       = 0.001f;

__device__ __forceinline__ float wave_sum(float v) {
#pragma unroll
    for (int off = 32; off > 0; off >>= 1) v += __shfl_down(v, off, 64);
    return v;
}

// ---------------- pass1 body (dim-split, R4-proven) ----------------
// GPB = float4 groups this block covers (each half-wave covers all of them
// for its own dim-plane). Requires GPB % 64 == 0.
template<int GPB>
__device__ __forceinline__ void p1_body(const float* __restrict__ emb,
                                        const int* __restrict__ mask,
                                        float* __restrict__ sums,
                                        float* __restrict__ cnts,
                                        const int b, const int blk) {
    const int wave = threadIdx.x >> 6;
    const int lane = threadIdx.x & 63;
    const int gl   = lane & 31;
    const int d    = wave * 2 + (lane >> 5);
    const bool dzero = (d == 0);

    const float4* __restrict__ ep = (const float4*)emb + (long)(b * ND + d) * NG;
    const int4*   __restrict__ mp = (const int4*)mask + (long)b * NG;

    float a0 = 0.f, a1 = 0.f, a2 = 0.f, a3 = 0.f, a4 = 0.f;
    float n0 = 0.f, n1 = 0.f, n2 = 0.f, n3 = 0.f, n4 = 0.f;

    const int base = blk * GPB + gl;
    constexpr int IT = GPB / 32;

#define PIX1(LAB, EJ) { const int lab = (LAB); const float ej = (EJ); \
        a0 += (lab == 1) ? ej : 0.f; a1 += (lab == 2) ? ej : 0.f; \
        a2 += (lab == 3) ? ej : 0.f; a3 += (lab == 4) ? ej : 0.f; \
        a4 += (lab == 5) ? ej : 0.f; \
        if (dzero) { n0 += (lab == 1) ? 1.f : 0.f; n1 += (lab == 2) ? 1.f : 0.f; \
                     n2 += (lab == 3) ? 1.f : 0.f; n3 += (lab == 4) ? 1.f : 0.f; \
                     n4 += (lab == 5) ? 1.f : 0.f; } }

#pragma unroll
    for (int it = 0; it < IT; it += 2) {
        const int ga = base + it * 32;
        const int gb = ga + 32;
        const int4   ma = mp[ga];
        const float4 ea = ep[ga];
        const int4   mb = mp[gb];
        const float4 eb = ep[gb];
        PIX1(ma.x, ea.x) PIX1(ma.y, ea.y) PIX1(ma.z, ea.z) PIX1(ma.w, ea.w)
        PIX1(mb.x, eb.x) PIX1(mb.y, eb.y) PIX1(mb.z, eb.z) PIX1(mb.w, eb.w)
    }
#undef PIX1

    // reduce within each 32-lane half (each half owns one dim -> final for block)
#pragma unroll
    for (int off = 16; off > 0; off >>= 1) {
        a0 += __shfl_down(a0, off, 32); a1 += __shfl_down(a1, off, 32);
        a2 += __shfl_down(a2, off, 32); a3 += __shfl_down(a3, off, 32);
        a4 += __shfl_down(a4, off, 32);
    }
    if (wave == 0) {
#pragma unroll
        for (int off = 16; off > 0; off >>= 1) {
            n0 += __shfl_down(n0, off, 32); n1 += __shfl_down(n1, off, 32);
            n2 += __shfl_down(n2, off, 32); n3 += __shfl_down(n3, off, 32);
            n4 += __shfl_down(n4, off, 32);
        }
    }

    __shared__ float pl[ND][NK];
    __shared__ float pc[NK];
    if (gl == 0) {
        pl[d][0] = a0; pl[d][1] = a1; pl[d][2] = a2; pl[d][3] = a3; pl[d][4] = a4;
    }
    if (threadIdx.x == 0) { pc[0] = n0; pc[1] = n1; pc[2] = n2; pc[3] = n3; pc[4] = n4; }
    __syncthreads();
    const int t = threadIdx.x;
    if (t < NK * ND)                       // t = k*8 + d
        atomicAdd(&sums[b * NK * ND + t], pl[t & 7][t >> 3]);
    else if (t < NVAL)
        atomicAdd(&cnts[b * NK + (t - NK * ND)], pc[t - NK * ND]);
}

// ---------------- pass2 body (fat form, R2/R4-proven) ----------------
template<int GPB>
__device__ __forceinline__ void p2_body(const float* __restrict__ emb,
                                        const int* __restrict__ mask,
                                        const float* __restrict__ sums,
                                        const float* __restrict__ cnts,
                                        float* __restrict__ vsums,
                                        const int b, const int blk) {
    const long base = (long)blk * GPB;

    // centers in named registers (wave-uniform loads -> compiler scalarizes)
    const float* sp = sums + b * NK * ND;
    const float i0 = 1.f / fmaxf(cnts[b * NK + 0], 1.f);
    const float i1 = 1.f / fmaxf(cnts[b * NK + 1], 1.f);
    const float i2 = 1.f / fmaxf(cnts[b * NK + 2], 1.f);
    const float i3 = 1.f / fmaxf(cnts[b * NK + 3], 1.f);
    const float i4 = 1.f / fmaxf(cnts[b * NK + 4], 1.f);
    const float4 c0l = make_float4(sp[0]*i0,  sp[1]*i0,  sp[2]*i0,  sp[3]*i0);
    const float4 c0h = make_float4(sp[4]*i0,  sp[5]*i0,  sp[6]*i0,  sp[7]*i0);
    const float4 c1l = make_float4(sp[8]*i1,  sp[9]*i1,  sp[10]*i1, sp[11]*i1);
    const float4 c1h = make_float4(sp[12]*i1, sp[13]*i1, sp[14]*i1, sp[15]*i1);
    const float4 c2l = make_float4(sp[16]*i2, sp[17]*i2, sp[18]*i2, sp[19]*i2);
    const float4 c2h = make_float4(sp[20]*i2, sp[21]*i2, sp[22]*i2, sp[23]*i2);
    const float4 c3l = make_float4(sp[24]*i3, sp[25]*i3, sp[26]*i3, sp[27]*i3);
    const float4 c3h = make_float4(sp[28]*i3, sp[29]*i3, sp[30]*i3, sp[31]*i3);
    const float4 c4l = make_float4(sp[32]*i4, sp[33]*i4, sp[34]*i4, sp[35]*i4);
    const float4 c4h = make_float4(sp[36]*i4, sp[37]*i4, sp[38]*i4, sp[39]*i4);

    const float4* __restrict__ emb4 = (const float4*)emb + (long)b * ND * NG;
    const int4*   __restrict__ m4p  = (const int4*)mask + (long)b * NG;

    float v0 = 0.f, v1 = 0.f, v2 = 0.f, v3 = 0.f, v4 = 0.f;

    for (int it = threadIdx.x; it < GPB; it += 256) {
        const long g = base + it;
        const int4   m  = m4p[g];
        const float4 e0 = emb4[g];
        const float4 e1 = emb4[g + (long)NG];
        const float4 e2 = emb4[g + 2L * NG];
        const float4 e3 = emb4[g + 3L * NG];
        const float4 e4 = emb4[g + 4L * NG];
        const float4 e5 = emb4[g + 5L * NG];
        const float4 e6 = emb4[g + 6L * NG];
        const float4 e7 = emb4[g + 7L * NG];

#define SEL2(F) ((lab == 1) ? c0##F : (lab == 2) ? c1##F : (lab == 3) ? c2##F : \
                 (lab == 4) ? c3##F : c4##F)
#define PIX2(LAB, CM) { const int lab = (LAB); \
        float dd = e0.CM - SEL2(l.x); float dsq = dd * dd; \
        dd = e1.CM - SEL2(l.y); dsq = fmaf(dd, dd, dsq); \
        dd = e2.CM - SEL2(l.z); dsq = fmaf(dd, dd, dsq); \
        dd = e3.CM - SEL2(l.w); dsq = fmaf(dd, dd, dsq); \
        dd = e4.CM - SEL2(h.x); dsq = fmaf(dd, dd, dsq); \
        dd = e5.CM - SEL2(h.y); dsq = fmaf(dd, dd, dsq); \
        dd = e6.CM - SEL2(h.z); dsq = fmaf(dd, dd, dsq); \
        dd = e7.CM - SEL2(h.w); dsq = fmaf(dd, dd, dsq); \
        const float dist = sqrtf(dsq); \
        const float hv = fmaxf(dist - DELTA_V, 0.f); \
        const float val = hv * hv; \
        v0 += (lab == 1) ? val : 0.f; v1 += (lab == 2) ? val : 0.f; \
        v2 += (lab == 3) ? val : 0.f; v3 += (lab == 4) ? val : 0.f; \
        v4 += (lab == 5) ? val : 0.f; }

        PIX2(m.x, x) PIX2(m.y, y) PIX2(m.z, z) PIX2(m.w, w)
#undef PIX2
#undef SEL2
    }

    __shared__ float part[4][NK];
    const int lane = threadIdx.x & 63;
    const int wave = threadIdx.x >> 6;
#define RED2(V, IDX) { const float r = wave_sum(V); if (lane == 0) part[wave][IDX] = r; }
    RED2(v0, 0) RED2(v1, 1) RED2(v2, 2) RED2(v3, 3) RED2(v4, 4)
#undef RED2
    __syncthreads();
    if (threadIdx.x < NK) {
        const float s = part[0][threadIdx.x] + part[1][threadIdx.x] +
                        part[2][threadIdx.x] + part[3][threadIdx.x];
        atomicAdd(&vsums[b * NK + threadIdx.x], s);
    }
}

// ---------------- Pipelined kernels ----------------
// P1A: pass1 for images 0..3. 2048 blocks = 512/image, 256 groups each.
__global__ __launch_bounds__(256) void p1a_kernel(const float* __restrict__ emb,
                                                  const int* __restrict__ mask,
                                                  float* __restrict__ sums,
                                                  float* __restrict__ cnts) {
    const int b   = blockIdx.x >> 9;          // /512
    const int blk = blockIdx.x & 511;
    p1_body<256>(emb, mask, sums, cnts, b, blk);
}

// MIX: pass1 images 4..7 (blocks 0..1023) || pass2 images 0..3 (blocks 1024..2047).
// Per-CU mixture of read-roles doubles memory-level parallelism (the A/B test).
__global__ __launch_bounds__(256) void mix_kernel(const float* __restrict__ emb,
                                                  const int* __restrict__ mask,
                                                  float* __restrict__ sums,
                                                  float* __restrict__ cnts,
                                                  float* __restrict__ vsums) {
    if (blockIdx.x < 1024) {
        const int b   = 4 + (blockIdx.x >> 8);   // /256
        const int blk = blockIdx.x & 255;
        p1_body<512>(emb, mask, sums, cnts, b, blk);
    } else {
        const int idx = blockIdx.x - 1024;
        const int b   = idx >> 8;
        const int blk = idx & 255;
        p2_body<512>(emb, mask, sums, cnts, vsums, b, blk);
    }
}

// P2B: pass2 for images 4..7. 2048 blocks = 512/image, 256 groups each.
__global__ __launch_bounds__(256) void p2b_kernel(const float* __restrict__ emb,
                                                  const int* __restrict__ mask,
                                                  const float* __restrict__ sums,
                                                  const float* __restrict__ cnts,
                                                  float* __restrict__ vsums) {
    const int b   = 4 + (blockIdx.x >> 9);
    const int blk = blockIdx.x & 511;
    p2_body<256>(emb, mask, sums, cnts, vsums, b, blk);
}

// ---------------- Final: tiny O(B*K^2) epilogue, 8-way parallel over batch ----------------
__global__ void final_kernel(const float* __restrict__ sums,
                             const float* __restrict__ cnts,
                             const float* __restrict__ vsums,
                             float* __restrict__ out) {
    __shared__ float bl[4][NB];
    const int bb = threadIdx.x;
    if (bb < NB) {
        float cc[NK];
        bool  pres[NK];
        float c[NK][ND];
        float N = 0.f;
#pragma unroll
        for (int k = 0; k < NK; ++k) {
            cc[k]   = cnts[bb * NK + k];
            pres[k] = cc[k] > 0.f;
            if (pres[k]) N += 1.f;
            const float inv = 1.f / fmaxf(cc[k], 1.f);
#pragma unroll
            for (int d = 0; d < ND; ++d)
                c[k][d] = sums[bb * NK * ND + k * ND + d] * inv;
        }
        // variance loss
        float lv = 0.f;
#pragma unroll
        for (int k = 0; k < NK; ++k)
            if (pres[k]) lv += vsums[bb * NK + k] / fmaxf(cc[k], 1.f);
        lv /= fmaxf(N, 1.f);
        // distance loss (pairwise i<j)
        float ld = 0.f;
#pragma unroll
        for (int i = 0; i < NK; ++i)
#pragma unroll
            for (int j = i + 1; j < NK; ++j)
                if (pres[i] && pres[j]) {
                    float dsq = 0.f;
#pragma unroll
                    for (int d = 0; d < ND; ++d) {
                        const float df = c[i][d] - c[j][d];
                        dsq = fmaf(df, df, dsq);
                    }
                    const float t = fmaxf(TWO_DELTA_D - sqrtf(dsq), 0.f);
                    ld += t * t;
                }
        const float npairs = N * (N - 1.f) * 0.5f;
        ld /= (N > 1.f) ? npairs : 1.f;
        // regularization
        float lr = 0.f;
#pragma unroll
        for (int k = 0; k < NK; ++k)
            if (pres[k]) {
                float sq = 0.f;
#pragma unroll
                for (int d = 0; d < ND; ++d) sq = fmaf(c[k][d], c[k][d], sq);
                lr += sqrtf(sq);
            }
        lr /= fmaxf(N, 1.f);

        const float has = (N > 0.f) ? 1.f : 0.f;
        bl[0][bb] = lv * has;
        bl[1][bb] = ld * has;
        bl[2][bb] = lr * has;
        bl[3][bb] = has;
    }
    __syncthreads();
    if (threadIdx.x == 0) {
        float tv = 0.f, td = 0.f, tr = 0.f, hs = 0.f;
        for (int i = 0; i < NB; ++i) {
            tv += bl[0][i]; td += bl[1][i]; tr += bl[2][i]; hs += bl[3][i];
        }
        const float denom = fmaxf(hs, 1.f);
        tv /= denom; td /= denom; tr /= denom;
        out[0] = tv + td + GAMMA * tr;
        out[1] = tv;
        out[2] = td;
        out[3] = tr;
    }
}

extern "C" void kernel_launch(void* const* d_in, const int* in_sizes, int n_in,
                              void* d_out, int out_size, void* d_ws, size_t ws_size,
                              hipStream_t stream) {
    const float* emb  = (const float*)d_in[0];
    const int*   mask = (const int*)d_in[1];
    float* out = (float*)d_out;

    float* sums  = (float*)d_ws;                 // NB*NK*ND = 320 floats
    float* cnts  = sums + NB * NK * ND;          // NB*NK    = 40
    float* vsums = cnts + NB * NK;               // NB*NK    = 40

    hipMemsetAsync(d_ws, 0, (size_t)(NB * NK * ND + 2 * NB * NK) * sizeof(float), stream);

    p1a_kernel<<<dim3(2048), dim3(256), 0, stream>>>(emb, mask, sums, cnts);
    mix_kernel<<<dim3(2048), dim3(256), 0, stream>>>(emb, mask, sums, cnts, vsums);
    p2b_kernel<<<dim3(2048), dim3(256), 0, stream>>>(emb, mask, sums, cnts, vsums);
    final_kernel<<<1, 64, 0, stream>>>(sums, cnts, vsums, out);
}

// Round 6
// 256.487 us; speedup vs baseline: 1.1293x; 1.1293x over previous
//
#include <hip/hip_runtime.h>
#include <math.h>

// Problem constants (match reference)
constexpr int NB   = 8;            // batch
constexpr int ND   = 8;            // embedding dim
constexpr int NH   = 512;
constexpr int NW   = 1024;
constexpr int NP   = NH * NW;      // pixels per image = 524288
constexpr int NG   = NP / 4;       // float4 groups per image = 131072
constexpr int NK   = 5;            // instance labels 1..NK

constexpr int BPB1 = 256;          // pass1 blocks per image (2048 total)
constexpr int GPB1 = NG / BPB1;    // 512 float4 groups per block
constexpr int IT1  = GPB1 / 32;    // 16 iterations (32 groups per iter per half-wave)
constexpr int BPB2 = 256;          // pass2 blocks per image (2048 total)
constexpr int GPB2 = NG / BPB2;    // 512 groups per block

constexpr float DELTA_V     = 0.5f;
constexpr float TWO_DELTA_D = 6.0f;   // 2 * DELTA_D
constexpr float GAMMA       = 0.001f;

// ext_vector types so __builtin_nontemporal_load works (HIP float4/int4 are
// structs, which the builtin rejects; ext_vector keeps .x/.y/.z/.w access).
typedef float f32x4 __attribute__((ext_vector_type(4)));
typedef int   i32x4 __attribute__((ext_vector_type(4)));

__device__ __forceinline__ float wave_sum(float v) {
#pragma unroll
    for (int off = 32; off > 0; off >>= 1) v += __shfl_down(v, off, 64);
    return v;
}

// ---------------- Pass 1: per-(b,k) embedding sums + counts ----------------
// Dim-split (R4-proven): wave w handles dims {2w, 2w+1}; each 32-lane half-wave
// owns one embedding plane. ONE CHANGE vs R4: emb loads are non-temporal
// (streaming, no L2 allocate). Mask stays a normal load: 8-way intra-block
// reuse across dim half-waves lives in L1/L2.
__global__ __launch_bounds__(256) void pass1_kernel(const float* __restrict__ emb,
                                                    const int* __restrict__ mask,
                                                    float* __restrict__ sums,   // [NB][NK][ND]
                                                    float* __restrict__ cnts) { // [NB][NK]
    const int b    = blockIdx.x / BPB1;
    const int blk  = blockIdx.x % BPB1;
    const int wave = threadIdx.x >> 6;
    const int lane = threadIdx.x & 63;
    const int gl   = lane & 31;
    const int d    = wave * 2 + (lane >> 5);
    const bool dzero = (d == 0);

    const f32x4* __restrict__ ep = (const f32x4*)emb + (long)(b * ND + d) * NG;
    const int4*  __restrict__ mp = (const int4*)mask + (long)b * NG;

    float a0 = 0.f, a1 = 0.f, a2 = 0.f, a3 = 0.f, a4 = 0.f;
    float n0 = 0.f, n1 = 0.f, n2 = 0.f, n3 = 0.f, n4 = 0.f;

    const int base = blk * GPB1 + gl;

#define PIX1(LAB, EJ) { const int lab = (LAB); const float ej = (EJ); \
        a0 += (lab == 1) ? ej : 0.f; a1 += (lab == 2) ? ej : 0.f; \
        a2 += (lab == 3) ? ej : 0.f; a3 += (lab == 4) ? ej : 0.f; \
        a4 += (lab == 5) ? ej : 0.f; \
        if (dzero) { n0 += (lab == 1) ? 1.f : 0.f; n1 += (lab == 2) ? 1.f : 0.f; \
                     n2 += (lab == 3) ? 1.f : 0.f; n3 += (lab == 4) ? 1.f : 0.f; \
                     n4 += (lab == 5) ? 1.f : 0.f; } }

#pragma unroll
    for (int it = 0; it < IT1; it += 2) {
        const int ga = base + it * 32;
        const int gb = ga + 32;
        const int4  ma = mp[ga];
        const f32x4 ea = __builtin_nontemporal_load(ep + ga);
        const int4  mb = mp[gb];
        const f32x4 eb = __builtin_nontemporal_load(ep + gb);
        PIX1(ma.x, ea.x) PIX1(ma.y, ea.y) PIX1(ma.z, ea.z) PIX1(ma.w, ea.w)
        PIX1(mb.x, eb.x) PIX1(mb.y, eb.y) PIX1(mb.z, eb.z) PIX1(mb.w, eb.w)
    }
#undef PIX1

    // reduce within each 32-lane half (each half owns one dim -> final for block)
#pragma unroll
    for (int off = 16; off > 0; off >>= 1) {
        a0 += __shfl_down(a0, off, 32); a1 += __shfl_down(a1, off, 32);
        a2 += __shfl_down(a2, off, 32); a3 += __shfl_down(a3, off, 32);
        a4 += __shfl_down(a4, off, 32);
    }
    if (wave == 0) {
#pragma unroll
        for (int off = 16; off > 0; off >>= 1) {
            n0 += __shfl_down(n0, off, 32); n1 += __shfl_down(n1, off, 32);
            n2 += __shfl_down(n2, off, 32); n3 += __shfl_down(n3, off, 32);
            n4 += __shfl_down(n4, off, 32);
        }
    }

    __shared__ float pl[ND][NK];
    __shared__ float pc[NK];
    if (gl == 0) {
        pl[d][0] = a0; pl[d][1] = a1; pl[d][2] = a2; pl[d][3] = a3; pl[d][4] = a4;
    }
    if (threadIdx.x == 0) { pc[0] = n0; pc[1] = n1; pc[2] = n2; pc[3] = n3; pc[4] = n4; }
    __syncthreads();
    const int t = threadIdx.x;
    if (t < NK * ND)                       // t = k*8 + d
        atomicAdd(&sums[b * NK * ND + t], pl[t & 7][t >> 3]);
    else if (t < NK * ND + NK)
        atomicAdd(&cnts[b * NK + (t - NK * ND)], pc[t - NK * ND]);
}

// ---------------- Pass 2: per-(b,k) variance hinge sums ----------------
// R2/R4-proven body; ONE CHANGE: all streaming loads (emb + mask) non-temporal.
__global__ __launch_bounds__(256) void pass2_kernel(const float* __restrict__ emb,
                                                    const int* __restrict__ mask,
                                                    const float* __restrict__ sums,
                                                    const float* __restrict__ cnts,
                                                    float* __restrict__ vsums) { // [NB][NK]
    const int b   = blockIdx.x / BPB2;
    const int blk = blockIdx.x % BPB2;
    const long base = (long)blk * GPB2;

    // centers in named registers (wave-uniform loads -> compiler scalarizes)
    const float* sp = sums + b * NK * ND;
    const float i0 = 1.f / fmaxf(cnts[b * NK + 0], 1.f);
    const float i1 = 1.f / fmaxf(cnts[b * NK + 1], 1.f);
    const float i2 = 1.f / fmaxf(cnts[b * NK + 2], 1.f);
    const float i3 = 1.f / fmaxf(cnts[b * NK + 3], 1.f);
    const float i4 = 1.f / fmaxf(cnts[b * NK + 4], 1.f);
    const float4 c0l = make_float4(sp[0]*i0,  sp[1]*i0,  sp[2]*i0,  sp[3]*i0);
    const float4 c0h = make_float4(sp[4]*i0,  sp[5]*i0,  sp[6]*i0,  sp[7]*i0);
    const float4 c1l = make_float4(sp[8]*i1,  sp[9]*i1,  sp[10]*i1, sp[11]*i1);
    const float4 c1h = make_float4(sp[12]*i1, sp[13]*i1, sp[14]*i1, sp[15]*i1);
    const float4 c2l = make_float4(sp[16]*i2, sp[17]*i2, sp[18]*i2, sp[19]*i2);
    const float4 c2h = make_float4(sp[20]*i2, sp[21]*i2, sp[22]*i2, sp[23]*i2);
    const float4 c3l = make_float4(sp[24]*i3, sp[25]*i3, sp[26]*i3, sp[27]*i3);
    const float4 c3h = make_float4(sp[28]*i3, sp[29]*i3, sp[30]*i3, sp[31]*i3);
    const float4 c4l = make_float4(sp[32]*i4, sp[33]*i4, sp[34]*i4, sp[35]*i4);
    const float4 c4h = make_float4(sp[36]*i4, sp[37]*i4, sp[38]*i4, sp[39]*i4);

    const f32x4* __restrict__ emb4 = (const f32x4*)emb + (long)b * ND * NG;
    const i32x4* __restrict__ m4p  = (const i32x4*)mask + (long)b * NG;

    float v0 = 0.f, v1 = 0.f, v2 = 0.f, v3 = 0.f, v4 = 0.f;

    for (int it = threadIdx.x; it < GPB2; it += 256) {
        const long g = base + it;
        const i32x4 m  = __builtin_nontemporal_load(m4p + g);
        const f32x4 e0 = __builtin_nontemporal_load(emb4 + g);
        const f32x4 e1 = __builtin_nontemporal_load(emb4 + g + (long)NG);
        const f32x4 e2 = __builtin_nontemporal_load(emb4 + g + 2L * NG);
        const f32x4 e3 = __builtin_nontemporal_load(emb4 + g + 3L * NG);
        const f32x4 e4 = __builtin_nontemporal_load(emb4 + g + 4L * NG);
        const f32x4 e5 = __builtin_nontemporal_load(emb4 + g + 5L * NG);
        const f32x4 e6 = __builtin_nontemporal_load(emb4 + g + 6L * NG);
        const f32x4 e7 = __builtin_nontemporal_load(emb4 + g + 7L * NG);

#define SEL2(F) ((lab == 1) ? c0##F : (lab == 2) ? c1##F : (lab == 3) ? c2##F : \
                 (lab == 4) ? c3##F : c4##F)
#define PIX2(LAB, CM) { const int lab = (LAB); \
        float dd = e0.CM - SEL2(l.x); float dsq = dd * dd; \
        dd = e1.CM - SEL2(l.y); dsq = fmaf(dd, dd, dsq); \
        dd = e2.CM - SEL2(l.z); dsq = fmaf(dd, dd, dsq); \
        dd = e3.CM - SEL2(l.w); dsq = fmaf(dd, dd, dsq); \
        dd = e4.CM - SEL2(h.x); dsq = fmaf(dd, dd, dsq); \
        dd = e5.CM - SEL2(h.y); dsq = fmaf(dd, dd, dsq); \
        dd = e6.CM - SEL2(h.z); dsq = fmaf(dd, dd, dsq); \
        dd = e7.CM - SEL2(h.w); dsq = fmaf(dd, dd, dsq); \
        const float dist = sqrtf(dsq); \
        const float hv = fmaxf(dist - DELTA_V, 0.f); \
        const float val = hv * hv; \
        v0 += (lab == 1) ? val : 0.f; v1 += (lab == 2) ? val : 0.f; \
        v2 += (lab == 3) ? val : 0.f; v3 += (lab == 4) ? val : 0.f; \
        v4 += (lab == 5) ? val : 0.f; }

        PIX2(m.x, x) PIX2(m.y, y) PIX2(m.z, z) PIX2(m.w, w)
#undef PIX2
#undef SEL2
    }

    __shared__ float part[4][NK];
    const int lane = threadIdx.x & 63;
    const int wave = threadIdx.x >> 6;
#define RED2(V, IDX) { const float r = wave_sum(V); if (lane == 0) part[wave][IDX] = r; }
    RED2(v0, 0) RED2(v1, 1) RED2(v2, 2) RED2(v3, 3) RED2(v4, 4)
#undef RED2
    __syncthreads();
    if (threadIdx.x < NK) {
        const float s = part[0][threadIdx.x] + part[1][threadIdx.x] +
                        part[2][threadIdx.x] + part[3][threadIdx.x];
        atomicAdd(&vsums[b * NK + threadIdx.x], s);
    }
}

// ---------------- Final: tiny O(B*K^2) epilogue, 8-way parallel over batch ----------------
__global__ void final_kernel(const float* __restrict__ sums,
                             const float* __restrict__ cnts,
                             const float* __restrict__ vsums,
                             float* __restrict__ out) {
    __shared__ float bl[4][NB];
    const int bb = threadIdx.x;
    if (bb < NB) {
        float cc[NK];
        bool  pres[NK];
        float c[NK][ND];
        float N = 0.f;
#pragma unroll
        for (int k = 0; k < NK; ++k) {
            cc[k]   = cnts[bb * NK + k];
            pres[k] = cc[k] > 0.f;
            if (pres[k]) N += 1.f;
            const float inv = 1.f / fmaxf(cc[k], 1.f);
#pragma unroll
            for (int d = 0; d < ND; ++d)
                c[k][d] = sums[bb * NK * ND + k * ND + d] * inv;
        }
        // variance loss
        float lv = 0.f;
#pragma unroll
        for (int k = 0; k < NK; ++k)
            if (pres[k]) lv += vsums[bb * NK + k] / fmaxf(cc[k], 1.f);
        lv /= fmaxf(N, 1.f);
        // distance loss (pairwise i<j)
        float ld = 0.f;
#pragma unroll
        for (int i = 0; i < NK; ++i)
#pragma unroll
            for (int j = i + 1; j < NK; ++j)
                if (pres[i] && pres[j]) {
                    float dsq = 0.f;
#pragma unroll
                    for (int d = 0; d < ND; ++d) {
                        const float df = c[i][d] - c[j][d];
                        dsq = fmaf(df, df, dsq);
                    }
                    const float t = fmaxf(TWO_DELTA_D - sqrtf(dsq), 0.f);
                    ld += t * t;
                }
        const float npairs = N * (N - 1.f) * 0.5f;
        ld /= (N > 1.f) ? npairs : 1.f;
        // regularization
        float lr = 0.f;
#pragma unroll
        for (int k = 0; k < NK; ++k)
            if (pres[k]) {
                float sq = 0.f;
#pragma unroll
                for (int d = 0; d < ND; ++d) sq = fmaf(c[k][d], c[k][d], sq);
                lr += sqrtf(sq);
            }
        lr /= fmaxf(N, 1.f);

        const float has = (N > 0.f) ? 1.f : 0.f;
        bl[0][bb] = lv * has;
        bl[1][bb] = ld * has;
        bl[2][bb] = lr * has;
        bl[3][bb] = has;
    }
    __syncthreads();
    if (threadIdx.x == 0) {
        float tv = 0.f, td = 0.f, tr = 0.f, hs = 0.f;
        for (int i = 0; i < NB; ++i) {
            tv += bl[0][i]; td += bl[1][i]; tr += bl[2][i]; hs += bl[3][i];
        }
        const float denom = fmaxf(hs, 1.f);
        tv /= denom; td /= denom; tr /= denom;
        out[0] = tv + td + GAMMA * tr;
        out[1] = tv;
        out[2] = td;
        out[3] = tr;
    }
}

extern "C" void kernel_launch(void* const* d_in, const int* in_sizes, int n_in,
                              void* d_out, int out_size, void* d_ws, size_t ws_size,
                              hipStream_t stream) {
    const float* emb  = (const float*)d_in[0];
    const int*   mask = (const int*)d_in[1];
    float* out = (float*)d_out;

    float* sums  = (float*)d_ws;                 // NB*NK*ND = 320 floats
    float* cnts  = sums + NB * NK * ND;          // NB*NK    = 40
    float* vsums = cnts + NB * NK;               // NB*NK    = 40

    hipMemsetAsync(d_ws, 0, (size_t)(NB * NK * ND + 2 * NB * NK) * sizeof(float), stream);

    pass1_kernel<<<dim3(NB * BPB1), dim3(256), 0, stream>>>(emb, mask, sums, cnts);
    pass2_kernel<<<dim3(NB * BPB2), dim3(256), 0, stream>>>(emb, mask, sums, cnts, vsums);
    final_kernel<<<1, 64, 0, stream>>>(sums, cnts, vsums, out);
}

// Round 7
// 255.430 us; speedup vs baseline: 1.1340x; 1.0041x over previous
//
#include <hip/hip_runtime.h>
#include <math.h>

// Problem constants (match reference)
constexpr int NB   = 8;            // batch
constexpr int ND   = 8;            // embedding dim
constexpr int NH   = 512;
constexpr int NW   = 1024;
constexpr int NP   = NH * NW;      // pixels per image = 524288
constexpr int NG   = NP / 4;       // float4 groups per image = 131072
constexpr int NK   = 5;            // instance labels 1..NK

constexpr int BPB1 = 256;          // pass1 blocks per image (2048 total)
constexpr int GPB1 = NG / BPB1;    // 512 float4 groups per block chunk
constexpr int BPB2 = 256;          // pass2 blocks per image (2048 total)
constexpr int GPB2 = NG / BPB2;    // 512 groups per block

constexpr float DELTA_V     = 0.5f;
constexpr float TWO_DELTA_D = 6.0f;   // 2 * DELTA_D
constexpr float GAMMA       = 0.001f;

// ext_vector types so __builtin_nontemporal_load works (pass2 only)
typedef float f32x4 __attribute__((ext_vector_type(4)));
typedef int   i32x4 __attribute__((ext_vector_type(4)));

__device__ __forceinline__ float wave_sum(float v) {
#pragma unroll
    for (int off = 32; off > 0; off >>= 1) v += __shfl_down(v, off, 64);
    return v;
}

// ---------------- Pass 1: per-(b,k) embedding sums + counts ----------------
// H7 plane-sequential form: thread t owns the SAME 8 pixels (groups t, t+256
// of the block's chunk) across all dims; labels live in m0/m1 registers
// (mask read ONCE per block, not 8x). The d-loop streams one contiguous 8KB
// plane-chunk at a time (one stream per block, fill-like), with explicit
// depth-1 prefetch rotation. Per-d accumulators wave-reduce into LDS.
__global__ __launch_bounds__(256) void pass1_kernel(const float* __restrict__ emb,
                                                    const int* __restrict__ mask,
                                                    float* __restrict__ sums,   // [NB][NK][ND]
                                                    float* __restrict__ cnts) { // [NB][NK]
    const int b    = blockIdx.x / BPB1;
    const int blk  = blockIdx.x % BPB1;
    const int t    = threadIdx.x;
    const int lane = t & 63;
    const int wave = t >> 6;

    __shared__ float psum[4][ND][NK];   // per-wave, per-dim, per-k partials
    __shared__ float pcnt[4][NK];

    const int4*   __restrict__ mp = (const int4*)mask + (long)b * NG + blk * GPB1;
    const float4* __restrict__ ep = (const float4*)emb + (long)b * ND * NG + blk * GPB1;

    // ---- labels: one mask read per block; counts directly from registers ----
    const int4 m0 = mp[t];
    const int4 m1 = mp[t + 256];

    float n0 = 0.f, n1 = 0.f, n2 = 0.f, n3 = 0.f, n4 = 0.f;
#define CNT1(L) { const int lb = (L); \
        n0 += (lb == 1) ? 1.f : 0.f; n1 += (lb == 2) ? 1.f : 0.f; \
        n2 += (lb == 3) ? 1.f : 0.f; n3 += (lb == 4) ? 1.f : 0.f; \
        n4 += (lb == 5) ? 1.f : 0.f; }
    CNT1(m0.x) CNT1(m0.y) CNT1(m0.z) CNT1(m0.w)
    CNT1(m1.x) CNT1(m1.y) CNT1(m1.z) CNT1(m1.w)
#undef CNT1
    n0 = wave_sum(n0); n1 = wave_sum(n1); n2 = wave_sum(n2);
    n3 = wave_sum(n3); n4 = wave_sum(n4);
    if (lane == 0) {
        pcnt[wave][0] = n0; pcnt[wave][1] = n1; pcnt[wave][2] = n2;
        pcnt[wave][3] = n3; pcnt[wave][4] = n4;
    }

    // ---- plane-sequential accumulation with depth-1 prefetch ----
    float4 ex = ep[t];
    float4 ey = ep[t + 256];
#pragma unroll 1
    for (int d = 0; d < ND; ++d) {
        const float4 cx = ex;
        const float4 cy = ey;
        if (d < ND - 1) {                       // prefetch next plane chunk
            ex = ep[(long)(d + 1) * NG + t];
            ey = ep[(long)(d + 1) * NG + t + 256];
        }
        float a0 = 0.f, a1 = 0.f, a2 = 0.f, a3 = 0.f, a4 = 0.f;
#define ACC1(EV, LB) { const int lb = (LB); const float e = (EV); \
        a0 += (lb == 1) ? e : 0.f; a1 += (lb == 2) ? e : 0.f; \
        a2 += (lb == 3) ? e : 0.f; a3 += (lb == 4) ? e : 0.f; \
        a4 += (lb == 5) ? e : 0.f; }
        ACC1(cx.x, m0.x) ACC1(cx.y, m0.y) ACC1(cx.z, m0.z) ACC1(cx.w, m0.w)
        ACC1(cy.x, m1.x) ACC1(cy.y, m1.y) ACC1(cy.z, m1.z) ACC1(cy.w, m1.w)
#undef ACC1
        a0 = wave_sum(a0); a1 = wave_sum(a1); a2 = wave_sum(a2);
        a3 = wave_sum(a3); a4 = wave_sum(a4);
        if (lane == 0) {
            psum[wave][d][0] = a0; psum[wave][d][1] = a1; psum[wave][d][2] = a2;
            psum[wave][d][3] = a3; psum[wave][d][4] = a4;
        }
    }
    __syncthreads();

    // ---- 45 atomics per block ----
    if (t < NK * ND) {                         // t = k*8 + d (matches sums layout)
        const int k = t >> 3, d = t & 7;
        const float s = psum[0][d][k] + psum[1][d][k] +
                        psum[2][d][k] + psum[3][d][k];
        atomicAdd(&sums[b * NK * ND + t], s);
    } else if (t < NK * ND + NK) {
        const int k = t - NK * ND;
        atomicAdd(&cnts[b * NK + k],
                  pcnt[0][k] + pcnt[1][k] + pcnt[2][k] + pcnt[3][k]);
    }
}

// ---------------- Pass 2: per-(b,k) variance hinge sums (R6-proven, nt loads) ----------------
__global__ __launch_bounds__(256) void pass2_kernel(const float* __restrict__ emb,
                                                    const int* __restrict__ mask,
                                                    const float* __restrict__ sums,
                                                    const float* __restrict__ cnts,
                                                    float* __restrict__ vsums) { // [NB][NK]
    const int b   = blockIdx.x / BPB2;
    const int blk = blockIdx.x % BPB2;
    const long base = (long)blk * GPB2;

    // centers in named registers (wave-uniform loads -> compiler scalarizes)
    const float* sp = sums + b * NK * ND;
    const float i0 = 1.f / fmaxf(cnts[b * NK + 0], 1.f);
    const float i1 = 1.f / fmaxf(cnts[b * NK + 1], 1.f);
    const float i2 = 1.f / fmaxf(cnts[b * NK + 2], 1.f);
    const float i3 = 1.f / fmaxf(cnts[b * NK + 3], 1.f);
    const float i4 = 1.f / fmaxf(cnts[b * NK + 4], 1.f);
    const float4 c0l = make_float4(sp[0]*i0,  sp[1]*i0,  sp[2]*i0,  sp[3]*i0);
    const float4 c0h = make_float4(sp[4]*i0,  sp[5]*i0,  sp[6]*i0,  sp[7]*i0);
    const float4 c1l = make_float4(sp[8]*i1,  sp[9]*i1,  sp[10]*i1, sp[11]*i1);
    const float4 c1h = make_float4(sp[12]*i1, sp[13]*i1, sp[14]*i1, sp[15]*i1);
    const float4 c2l = make_float4(sp[16]*i2, sp[17]*i2, sp[18]*i2, sp[19]*i2);
    const float4 c2h = make_float4(sp[20]*i2, sp[21]*i2, sp[22]*i2, sp[23]*i2);
    const float4 c3l = make_float4(sp[24]*i3, sp[25]*i3, sp[26]*i3, sp[27]*i3);
    const float4 c3h = make_float4(sp[28]*i3, sp[29]*i3, sp[30]*i3, sp[31]*i3);
    const float4 c4l = make_float4(sp[32]*i4, sp[33]*i4, sp[34]*i4, sp[35]*i4);
    const float4 c4h = make_float4(sp[36]*i4, sp[37]*i4, sp[38]*i4, sp[39]*i4);

    const f32x4* __restrict__ emb4 = (const f32x4*)emb + (long)b * ND * NG;
    const i32x4* __restrict__ m4p  = (const i32x4*)mask + (long)b * NG;

    float v0 = 0.f, v1 = 0.f, v2 = 0.f, v3 = 0.f, v4 = 0.f;

    for (int it = threadIdx.x; it < GPB2; it += 256) {
        const long g = base + it;
        const i32x4 m  = __builtin_nontemporal_load(m4p + g);
        const f32x4 e0 = __builtin_nontemporal_load(emb4 + g);
        const f32x4 e1 = __builtin_nontemporal_load(emb4 + g + (long)NG);
        const f32x4 e2 = __builtin_nontemporal_load(emb4 + g + 2L * NG);
        const f32x4 e3 = __builtin_nontemporal_load(emb4 + g + 3L * NG);
        const f32x4 e4 = __builtin_nontemporal_load(emb4 + g + 4L * NG);
        const f32x4 e5 = __builtin_nontemporal_load(emb4 + g + 5L * NG);
        const f32x4 e6 = __builtin_nontemporal_load(emb4 + g + 6L * NG);
        const f32x4 e7 = __builtin_nontemporal_load(emb4 + g + 7L * NG);

#define SEL2(F) ((lab == 1) ? c0##F : (lab == 2) ? c1##F : (lab == 3) ? c2##F : \
                 (lab == 4) ? c3##F : c4##F)
#define PIX2(LAB, CM) { const int lab = (LAB); \
        float dd = e0.CM - SEL2(l.x); float dsq = dd * dd; \
        dd = e1.CM - SEL2(l.y); dsq = fmaf(dd, dd, dsq); \
        dd = e2.CM - SEL2(l.z); dsq = fmaf(dd, dd, dsq); \
        dd = e3.CM - SEL2(l.w); dsq = fmaf(dd, dd, dsq); \
        dd = e4.CM - SEL2(h.x); dsq = fmaf(dd, dd, dsq); \
        dd = e5.CM - SEL2(h.y); dsq = fmaf(dd, dd, dsq); \
        dd = e6.CM - SEL2(h.z); dsq = fmaf(dd, dd, dsq); \
        dd = e7.CM - SEL2(h.w); dsq = fmaf(dd, dd, dsq); \
        const float dist = sqrtf(dsq); \
        const float hv = fmaxf(dist - DELTA_V, 0.f); \
        const float val = hv * hv; \
        v0 += (lab == 1) ? val : 0.f; v1 += (lab == 2) ? val : 0.f; \
        v2 += (lab == 3) ? val : 0.f; v3 += (lab == 4) ? val : 0.f; \
        v4 += (lab == 5) ? val : 0.f; }

        PIX2(m.x, x) PIX2(m.y, y) PIX2(m.z, z) PIX2(m.w, w)
#undef PIX2
#undef SEL2
    }

    __shared__ float part[4][NK];
    const int lane = threadIdx.x & 63;
    const int wave = threadIdx.x >> 6;
#define RED2(V, IDX) { const float r = wave_sum(V); if (lane == 0) part[wave][IDX] = r; }
    RED2(v0, 0) RED2(v1, 1) RED2(v2, 2) RED2(v3, 3) RED2(v4, 4)
#undef RED2
    __syncthreads();
    if (threadIdx.x < NK) {
        const float s = part[0][threadIdx.x] + part[1][threadIdx.x] +
                        part[2][threadIdx.x] + part[3][threadIdx.x];
        atomicAdd(&vsums[b * NK + threadIdx.x], s);
    }
}

// ---------------- Final: tiny O(B*K^2) epilogue, 8-way parallel over batch ----------------
__global__ void final_kernel(const float* __restrict__ sums,
                             const float* __restrict__ cnts,
                             const float* __restrict__ vsums,
                             float* __restrict__ out) {
    __shared__ float bl[4][NB];
    const int bb = threadIdx.x;
    if (bb < NB) {
        float cc[NK];
        bool  pres[NK];
        float c[NK][ND];
        float N = 0.f;
#pragma unroll
        for (int k = 0; k < NK; ++k) {
            cc[k]   = cnts[bb * NK + k];
            pres[k] = cc[k] > 0.f;
            if (pres[k]) N += 1.f;
            const float inv = 1.f / fmaxf(cc[k], 1.f);
#pragma unroll
            for (int d = 0; d < ND; ++d)
                c[k][d] = sums[bb * NK * ND + k * ND + d] * inv;
        }
        // variance loss
        float lv = 0.f;
#pragma unroll
        for (int k = 0; k < NK; ++k)
            if (pres[k]) lv += vsums[bb * NK + k] / fmaxf(cc[k], 1.f);
        lv /= fmaxf(N, 1.f);
        // distance loss (pairwise i<j)
        float ld = 0.f;
#pragma unroll
        for (int i = 0; i < NK; ++i)
#pragma unroll
            for (int j = i + 1; j < NK; ++j)
                if (pres[i] && pres[j]) {
                    float dsq = 0.f;
#pragma unroll
                    for (int d = 0; d < ND; ++d) {
                        const float df = c[i][d] - c[j][d];
                        dsq = fmaf(df, df, dsq);
                    }
                    const float t = fmaxf(TWO_DELTA_D - sqrtf(dsq), 0.f);
                    ld += t * t;
                }
        const float npairs = N * (N - 1.f) * 0.5f;
        ld /= (N > 1.f) ? npairs : 1.f;
        // regularization
        float lr = 0.f;
#pragma unroll
        for (int k = 0; k < NK; ++k)
            if (pres[k]) {
                float sq = 0.f;
#pragma unroll
                for (int d = 0; d < ND; ++d) sq = fmaf(c[k][d], c[k][d], sq);
                lr += sqrtf(sq);
            }
        lr /= fmaxf(N, 1.f);

        const float has = (N > 0.f) ? 1.f : 0.f;
        bl[0][bb] = lv * has;
        bl[1][bb] = ld * has;
        bl[2][bb] = lr * has;
        bl[3][bb] = has;
    }
    __syncthreads();
    if (threadIdx.x == 0) {
        float tv = 0.f, td = 0.f, tr = 0.f, hs = 0.f;
        for (int i = 0; i < NB; ++i) {
            tv += bl[0][i]; td += bl[1][i]; tr += bl[2][i]; hs += bl[3][i];
        }
        const float denom = fmaxf(hs, 1.f);
        tv /= denom; td /= denom; tr /= denom;
        out[0] = tv + td + GAMMA * tr;
        out[1] = tv;
        out[2] = td;
        out[3] = tr;
    }
}

extern "C" void kernel_launch(void* const* d_in, const int* in_sizes, int n_in,
                              void* d_out, int out_size, void* d_ws, size_t ws_size,
                              hipStream_t stream) {
    const float* emb  = (const float*)d_in[0];
    const int*   mask = (const int*)d_in[1];
    float* out = (float*)d_out;

    float* sums  = (float*)d_ws;                 // NB*NK*ND = 320 floats
    float* cnts  = sums + NB * NK * ND;          // NB*NK    = 40
    float* vsums = cnts + NB * NK;               // NB*NK    = 40

    hipMemsetAsync(d_ws, 0, (size_t)(NB * NK * ND + 2 * NB * NK) * sizeof(float), stream);

    pass1_kernel<<<dim3(NB * BPB1), dim3(256), 0, stream>>>(emb, mask, sums, cnts);
    pass2_kernel<<<dim3(NB * BPB2), dim3(256), 0, stream>>>(emb, mask, sums, cnts, vsums);
    final_kernel<<<1, 64, 0, stream>>>(sums, cnts, vsums, out);
}